// Round 1
// baseline (60.334 us; speedup 1.0000x reference)
//
#include <hip/hip_runtime.h>

// Problem: B=64, M=64, P=128, V=32. Output = 0.5 * min_{m,p} dist(last_point[63,m], poly[63,p])
// Only batch index 63 contributes (reference takes per_batch_min[-1]).
#define BNUM 64
#define MNUM 64
#define PNUM 128
#define VNUM 32
#define EPSF 1e-12f

// One block per polygon p (128 blocks), one thread per point m (64 threads = 1 wave).
__global__ void __launch_bounds__(64) poly_dist_kernel(
        const float* __restrict__ last_point,     // [B, M, 2]
        const float* __restrict__ polygon_coords, // [B, P, V, 2]
        float* __restrict__ ws)                   // [P] per-polygon min over m
{
    const int p = blockIdx.x;   // 0..127
    const int m = threadIdx.x;  // 0..63

    // Point for batch 63, point m.
    const float px = last_point[((BNUM - 1) * MNUM + m) * 2 + 0];
    const float py = last_point[((BNUM - 1) * MNUM + m) * 2 + 1];

    // Polygon verts for batch 63, polygon p -> LDS (tiny, broadcast-read later).
    __shared__ float vx[VNUM], vy[VNUM];
    const float* poly = polygon_coords + (size_t)(((BNUM - 1) * PNUM + p) * VNUM) * 2;
    if (m < VNUM) {
        vx[m] = poly[m * 2 + 0];
        vy[m] = poly[m * 2 + 1];
    }
    __syncthreads();

    float min_edge = 3.4e38f;
    int crossings = 0;
    #pragma unroll
    for (int v = 0; v < VNUM; ++v) {
        const float ax = vx[v],            ay = vy[v];
        const float bx = vx[(v + 1) & 31], by = vy[(v + 1) & 31];
        const float abx = bx - ax, aby = by - ay;
        const float apx = px - ax, apy = py - ay;

        // t = clip(dot(ap,ab)/(dot(ab,ab)+EPS), 0, 1)
        float t = (apx * abx + apy * aby) / (abx * abx + aby * aby + EPSF);
        t = fminf(fmaxf(t, 0.0f), 1.0f);
        const float dx = apx - t * abx;
        const float dy = apy - t * aby;
        const float d2 = fmaxf(dx * dx + dy * dy, EPSF);
        min_edge = fminf(min_edge, sqrtf(d2));

        // ray-crossing parity: straddles & (px < x_int)
        const bool straddle = (ay > py) != (by > py);
        const float x_int = ax + abx * apy / (aby + EPSF);
        crossings += (straddle && (px < x_int)) ? 1 : 0;
    }

    float dist = (crossings & 1) ? 0.0f : min_edge;

    // wave-64 min reduction
    #pragma unroll
    for (int off = 32; off > 0; off >>= 1)
        dist = fminf(dist, __shfl_down(dist, off, 64));

    if (m == 0) ws[p] = dist;
}

// Reduce 128 partial mins with a single wave; scale by 0.5.
__global__ void __launch_bounds__(64) final_reduce_kernel(
        const float* __restrict__ ws, float* __restrict__ out)
{
    const int i = threadIdx.x; // 0..63
    float v = fminf(ws[i], ws[i + 64]);
    #pragma unroll
    for (int off = 32; off > 0; off >>= 1)
        v = fminf(v, __shfl_down(v, off, 64));
    if (i == 0) out[0] = 0.5f * v;
}

extern "C" void kernel_launch(void* const* d_in, const int* in_sizes, int n_in,
                              void* d_out, int out_size, void* d_ws, size_t ws_size,
                              hipStream_t stream) {
    const float* last_point     = (const float*)d_in[0]; // [64,64,2]
    const float* polygon_coords = (const float*)d_in[1]; // [64,128,32,2]
    float* out = (float*)d_out;                          // scalar
    float* ws  = (float*)d_ws;                           // >= 128 floats

    poly_dist_kernel<<<dim3(PNUM), dim3(64), 0, stream>>>(last_point, polygon_coords, ws);
    final_reduce_kernel<<<dim3(1), dim3(64), 0, stream>>>(ws, out);
}